// Round 19
// baseline (811.719 us; speedup 1.0000x reference)
//
#include <hip/hip_runtime.h>
#include <stdint.h>

#define B_   4
#define T_   4096
#define D_   1024
#define H_   16
#define M_   16384
#define NTOT 1536
#define BM   64
#define BN   64
#define BK   32
#define KC   384   // OpenBLAS SGEMM_DEFAULT_Q (Haswell/Zen)

typedef unsigned short u16;
typedef unsigned long long u64;

__device__ __forceinline__ float bf16r(float f) {
    unsigned int u = __float_as_uint(f);
    u += 0x7FFFu + ((u >> 16) & 1u);
    return __uint_as_float(u & 0xFFFF0000u);
}

// ---------------------------------------------------------------------------
// GEMM on RAW f32 inputs replicating OpenBLAS sgemm accumulation order:
// serial FMA chain (ascending k, one accumulator per C element) within
// KC=384 panels; C += per panel: (P0 + P1) + P2 with panels 384/384/256.
// Sign-packs q/k 16-bit codes and v 64-bit codes.
// ---------------------------------------------------------------------------
__global__ __launch_bounds__(256) void gemm_pack_kernel(
    const float* __restrict__ x, const float* __restrict__ Wq,
    const float* __restrict__ Wk, const float* __restrict__ Wv,
    u16* __restrict__ qc, u16* __restrict__ kc, u64* __restrict__ vc)
{
    __shared__ float As[BM][BK + 1];
    __shared__ float Bs[BK][BN + 4];
    __shared__ unsigned char sub[BM][16];

    const int tid = threadIdx.x;
    const int tx = tid & 15, ty = tid >> 4;
    const int m0 = blockIdx.x * BM;
    const int n0 = blockIdx.y * BN;

    const float* Wsrc; int f0;
    if (n0 < 256)      { Wsrc = Wq; f0 = n0; }
    else if (n0 < 512) { Wsrc = Wk; f0 = n0 - 256; }
    else               { Wsrc = Wv; f0 = n0 - 512; }

    float run[4][4], tot[4][4];
    #pragma unroll
    for (int i = 0; i < 4; ++i)
        #pragma unroll
        for (int j = 0; j < 4; ++j) { run[i][j] = 0.f; tot[i][j] = 0.f; }

    const int r8 = tid >> 2;           // 0..63
    const int c8 = (tid & 3) * 8;      // 0,8,16,24

    for (int k0 = 0; k0 < D_; k0 += BK) {
        const float* xp = x + (size_t)(m0 + r8) * D_ + k0 + c8;
        float4 a0 = *(const float4*)xp, a1 = *(const float4*)(xp + 4);
        const float* wp = Wsrc + (size_t)(f0 + r8) * D_ + k0 + c8;
        float4 w0 = *(const float4*)wp, w1 = *(const float4*)(wp + 4);
        As[r8][c8 + 0] = a0.x; As[r8][c8 + 1] = a0.y;
        As[r8][c8 + 2] = a0.z; As[r8][c8 + 3] = a0.w;
        As[r8][c8 + 4] = a1.x; As[r8][c8 + 5] = a1.y;
        As[r8][c8 + 6] = a1.z; As[r8][c8 + 7] = a1.w;
        Bs[c8 + 0][r8] = w0.x; Bs[c8 + 1][r8] = w0.y;
        Bs[c8 + 2][r8] = w0.z; Bs[c8 + 3][r8] = w0.w;
        Bs[c8 + 4][r8] = w1.x; Bs[c8 + 5][r8] = w1.y;
        Bs[c8 + 6][r8] = w1.z; Bs[c8 + 7][r8] = w1.w;
        __syncthreads();

        #pragma unroll 4
        for (int k = 0; k < BK; ++k) {
            float a_[4], b_[4];
            #pragma unroll
            for (int i = 0; i < 4; ++i) a_[i] = As[ty * 4 + i][k];
            #pragma unroll
            for (int j = 0; j < 4; ++j) b_[j] = Bs[k][tx * 4 + j];
            #pragma unroll
            for (int i = 0; i < 4; ++i)
                #pragma unroll
                for (int j = 0; j < 4; ++j)
                    run[i][j] = __builtin_fmaf(a_[i], b_[j], run[i][j]);
        }
        __syncthreads();

        // OpenBLAS panel boundary: C += panel at k = 384 and 768.
        const int kend = k0 + BK;
        if (kend == KC || kend == 2 * KC) {
            #pragma unroll
            for (int i = 0; i < 4; ++i)
                #pragma unroll
                for (int j = 0; j < 4; ++j) {
                    tot[i][j] = tot[i][j] + run[i][j];
                    run[i][j] = 0.f;
                }
        }
    }

    #pragma unroll
    for (int i = 0; i < 4; ++i) {
        unsigned char byte = 0;
        #pragma unroll
        for (int j = 0; j < 4; ++j) {
            float v = tot[i][j] + run[i][j];   // final C = (P0+P1)+P2
            byte |= (unsigned char)((v > 0.0f) ? (1u << j) : 0u);
        }
        sub[ty * 4 + i][tx] = byte;
    }
    __syncthreads();

    if (tid < 64) {
        u64 row = 0ULL;
        #pragma unroll
        for (int c = 0; c < 16; ++c)
            row |= (u64)(sub[tid][c] & 0xFu) << (c * 4);
        const int m = m0 + tid;
        const int b = m >> 12;
        const int t = m & (T_ - 1);
        if (n0 < 512) {
            u16* dst = (n0 < 256) ? qc : kc;
            const int hb = (n0 & 255) >> 4;
            #pragma unroll
            for (int g = 0; g < 4; ++g)
                dst[((size_t)(b * H_ + hb + g)) * T_ + t] = (u16)((row >> (g * 16)) & 0xFFFFULL);
        } else {
            const int h = (n0 - 512) >> 6;
            vc[((size_t)(b * H_ + h)) * T_ + t] = row;
        }
    }
}

// ---------------------------------------------------------------------------
// Fused resolve + expand (structure proven correct in R16).
// ---------------------------------------------------------------------------
__global__ __launch_bounds__(256) void resolve_expand_kernel(
    const u16* __restrict__ qc, const u16* __restrict__ kc,
    const u64* __restrict__ vc,
    const float* __restrict__ emb0, const float* __restrict__ emb1,
    float* __restrict__ out)
{
    __shared__ u16 keys[T_];
    __shared__ u16 pos[T_];
    __shared__ unsigned int cnt[256];
    __shared__ unsigned int offs[257];
    __shared__ float e_lo[64], e_hi[64];

    const int bh = blockIdx.x;
    const int b = bh >> 4, h = bh & 15;
    const u16* kck = kc + (size_t)bh * T_;
    const u16* qck = qc + (size_t)bh * T_;
    const u64* vck = vc + (size_t)bh * T_;
    const int tid = threadIdx.x;

    if (tid < 64) {
        e_lo[tid] = bf16r(emb0[h * 64 + tid]);   // where-false (negative)
        e_hi[tid] = bf16r(emb1[h * 64 + tid]);   // where-true (positive)
    }
    cnt[tid] = 0;
    __syncthreads();
    for (int t = tid; t < T_; t += 256) {
        u16 kv = kck[t];
        keys[t] = kv;
        atomicAdd(&cnt[kv & 255], 1u);
    }
    __syncthreads();
    if (tid == 0) {
        unsigned int s = 0;
        for (int i = 0; i < 256; ++i) { offs[i] = s; s += cnt[i]; }
        offs[256] = s;
    }
    __syncthreads();
    cnt[tid] = offs[tid];
    __syncthreads();
    for (int t = tid; t < T_; t += 256) {
        unsigned int p = atomicAdd(&cnt[keys[t] & 255], 1u);
        pos[p] = (u16)t;
    }
    __syncthreads();
    for (int t = tid; t < T_; t += 256) {
        u16 code = qck[t];
        const int bkt = code & 255;
        int best = -1;
        const unsigned int s = offs[bkt], e = offs[bkt + 1];
        for (unsigned int it = s; it < e; ++it) {
            int j = (int)pos[it];
            if (j < t && keys[j] == code && j > best) best = j;
        }
        u64 yv = (best >= 0) ? vck[best] : 0ULL;
        float* orow = out + ((size_t)(b * T_ + t)) * D_ + h * 64;
        #pragma unroll
        for (int e2 = 0; e2 < 64; ++e2)
            orow[e2] = ((yv >> e2) & 1ULL) ? e_hi[e2] : e_lo[e2];
    }
}

// ---------------------------------------------------------------------------
extern "C" void kernel_launch(void* const* d_in, const int* in_sizes, int n_in,
                              void* d_out, int out_size, void* d_ws, size_t ws_size,
                              hipStream_t stream)
{
    const float* x  = (const float*)d_in[0];
    const float* Wq = (const float*)d_in[1];
    const float* Wk = (const float*)d_in[2];
    const float* Wv = (const float*)d_in[3];
    const float* e0 = (const float*)d_in[4];
    const float* e1 = (const float*)d_in[5];

    char* ws = (char*)d_ws;
    // footprint 3 MB (safe: ws_size >= ~5.3 MB): qc 512K | kc 512K | vc 2M
    u16* qc = (u16*)(ws + 0);
    u16* kc = (u16*)(ws + 524288);
    u64* vc = (u64*)(ws + 1048576);
    float* out = (float*)d_out;

    dim3 gA(M_ / BM, NTOT / BN);   // 256 x 24
    gemm_pack_kernel<<<gA, 256, 0, stream>>>(x, Wq, Wk, Wv, qc, kc, vc);
    resolve_expand_kernel<<<64, 256, 0, stream>>>(qc, kc, vc, e0, e1, out);
}